// Round 16
// baseline (98.848 us; speedup 1.0000x reference)
//
#include <hip/hip_runtime.h>
#include <hip/hip_bf16.h>
#include <math.h>

#define NSLICE 2048
#define NH 133     // output spatial size (int(128*1+4)+1)
#define NP 144     // padded to 9 tiles of 16
#define NT 576     // 9 waves per block

// LDS map (74,752 B; x2 = 149,504 <= 163,840 -> 2 blocks/CU):
//   [0, 65536)       X fp32, HALF-FRAGMENT-major: 64 hf x 1024 B;
//                    hf = (pt*4+kk)*2 + h; lane's 16 B at hf*1024 + lane*16
//                    holds X[pt*16 + (lane&15)][kk*32 + (lane>>4)*8 + h*4 ..+3]
//   [65536, 74752)   scratch: 9 waves x 1024 B (per-wave repack)
#define SCR  65536
#define LDSB 74752

typedef __attribute__((ext_vector_type(8))) short bf16x8;   // 8 bf16 = 4 VGPRs
typedef __attribute__((ext_vector_type(4))) float f32x4;

typedef __attribute__((address_space(3))) unsigned int  lds_u32;
typedef const __attribute__((address_space(1))) unsigned int glb_u32;

#define GLOAD_LDS16(gsrc, ldst) \
    __builtin_amdgcn_global_load_lds((glb_u32*)(gsrc), (lds_u32*)(ldst), 16, 0, 0)

__device__ __forceinline__ unsigned f2bf(float f) {
    __hip_bfloat16 h = __float2bfloat16(f);   // round-to-nearest-even
    union { __hip_bfloat16 b; unsigned short u; } c; c.b = h; return (unsigned)c.u;
}

// ---------------------------------------------------------------------------
// prep_M: combined (IDCT * mask * DCT) matrices, bf16, in workspace.
//   M[row, p] = sum_{u=0}^{127} D2[u,row] * mask[u] * D1[u,p]
// M1 emitted FRAGMENT-MAJOR (R10-proven): wave read
//   M1f + (it*4+kk)*512 + lane*8  is its stage-B A-fragment. M2 row-major.
// ---------------------------------------------------------------------------
__global__ void prep_M(const float* __restrict__ rw,
                       unsigned short* __restrict__ M1,
                       unsigned short* __restrict__ M2) {
    __shared__ float t1[512];
    __shared__ float t2[532];
    const int b   = blockIdx.x;        // 0..287
    const int m   = b / NP;            // 0 -> M1, 1 -> M2
    const int row = b - m * NP;        // 0..143
    const int p   = threadIdx.x;       // 0..127

    const float c1  = (float)(M_PI / 256.0);
    const float c2  = (float)(M_PI / 266.0);
    const float s1n = 0.125f;                  // sqrt(2/128)
    const float s10 = 0.08838834764831844f;    // s1n/sqrt(2)
    const float s2n = 0.12262786485246718f;    // sqrt(2/133)
    const float s20 = 0.08671099951921386f;    // s2n/sqrt(2)

    for (int k = p; k < 512; k += 128) t1[k] = cosf((float)k * c1) * s1n;
    for (int k = p; k < 532; k += 128) t2[k] = cosf((float)k * c2) * s2n;
    __syncthreads();

    float val = 0.0f;
    if (row < NH) {
        float r = rw[m];
        float minr = fmaxf((1.0f - 4.0f) / 128.0f, 0.0f);
        r = fminf(fmaxf(r, minr), 2.0f);
        const float crop = 128.0f * r;

        const int tp = 2 * p + 1;
        const int ti = 2 * row + 1;
        float acc = s10 * s20;        // u = 0 term (mask(0) == 1 since crop >= 0)
        int a1 = 0, a2 = 0;
        for (int u = 1; u < 128; ++u) {
            a1 = (a1 + tp) & 511;
            a2 += ti; if (a2 >= 532) a2 -= 532;
            float mask = fminf(fmaxf((4.0f + crop - (float)u) * 0.25f, 0.0f), 1.0f);
            acc = fmaf(t1[a1] * mask, t2[a2], acc);
        }
        val = acc;
    }
    const unsigned short v16 = (unsigned short)f2bf(val);
    if (m == 0) {
        const int it = row >> 4, rr = row & 15;
        const int k2 = p >> 5, gg = (p >> 3) & 3, e = p & 7;
        M1[(size_t)((it * 4 + k2) * 512 + (gg * 16 + rr) * 8 + e)] = v16;
    } else {
        M2[(size_t)row * 128 + p] = v16;
    }
}

// ---------------------------------------------------------------------------
// dct_resize: one 576-thread block (9 waves) per (b,c) slice, ONE barrier.
//   staging: 64 async global_load_lds (8 per wave, waves 0-7) place fp32 X
//     in half-fragment-major LDS -- fire-and-forget, zero staging VGPRs,
//     zero serial dependency; __syncthreads' built-in vmcnt(0) is the wait.
//     bm2 register fragments load concurrently.
//   post-barrier, waves fully independent:
//     Stage A: wave w owns j-tile w: per pt, 8 lane-contiguous ds_read_b128
//       (proven conflict-free), inline cvt fp32->bf16, 4 MFMA vs bm2.
//     repack : per-wave 1KB scratch (in-wave DS ordering, barrier-free)
//     Stage B: 36 MFMA, A-frags from global fragment-major M1 (L1/L2-hot,
//       R15-proven flat FETCH); guarded stores.
// ---------------------------------------------------------------------------
__global__ __launch_bounds__(NT, 5) void dct_resize(
        const float* __restrict__ x,
        const unsigned short* __restrict__ M1f,
        const unsigned short* __restrict__ M2,
        float* __restrict__ out) {
    __shared__ __align__(16) unsigned char lds[LDSB];

    const int tid  = threadIdx.x;
    const int w    = tid >> 6;      // wave 0..8
    const int lane = tid & 63;
    const int r    = lane & 15;     // fragment row/col index
    const int g    = lane >> 4;     // k-group 0..3

    const float* xs = x + (size_t)blockIdx.x * (128 * 128);
    float*       os = out + (size_t)blockIdx.x * (NH * NH);

    const int j0 = w * 16;          // this wave's output-column tile

    // ---- async X staging: wave w issues half-frags w*8 .. w*8+7 ----
    if (w < 8) {
        #pragma unroll
        for (int v = 0; v < 8; ++v) {
            const int hf = w * 8 + v;
            const int f  = hf >> 1, h = hf & 1;
            const int pt = f >> 2, k2 = f & 3;
            const float* src = xs + (size_t)(pt * 16 + r) * 128
                             + k2 * 32 + g * 8 + h * 4;
            GLOAD_LDS16(src, lds + hf * 1024);   // HW adds lane*16
        }
    }

    // ---- per-wave M2 register fragments (L2-hot), concurrent with staging ----
    bf16x8 bm2[4];
    #pragma unroll
    for (int kk = 0; kk < 4; ++kk)
        bm2[kk] = *(const bf16x8*)(M2 + (size_t)(j0 + r) * 128 + kk * 32 + g * 8);

    __syncthreads();   // the ONLY barrier; built-in vmcnt(0) drains gload_lds

    // ---- Stage A: T[j0+r][p] = sum_q X[p][q] * M2[j0+r][q] ----
    uint2 u2[8];
    #pragma unroll
    for (int pt = 0; pt < 8; ++pt) {
        f32x4 acc = {0.f, 0.f, 0.f, 0.f};
        #pragma unroll
        for (int kk = 0; kk < 4; ++kk) {
            const int hf = (pt * 4 + kk) * 2;
            const float4 lo = *(const float4*)(lds + hf * 1024 + lane * 16);
            const float4 hi = *(const float4*)(lds + hf * 1024 + 1024 + lane * 16);
            union { bf16x8 b; unsigned short us[8]; } fr;
            fr.us[0] = (unsigned short)f2bf(lo.x);
            fr.us[1] = (unsigned short)f2bf(lo.y);
            fr.us[2] = (unsigned short)f2bf(lo.z);
            fr.us[3] = (unsigned short)f2bf(lo.w);
            fr.us[4] = (unsigned short)f2bf(hi.x);
            fr.us[5] = (unsigned short)f2bf(hi.y);
            fr.us[6] = (unsigned short)f2bf(hi.z);
            fr.us[7] = (unsigned short)f2bf(hi.w);
            acc = __builtin_amdgcn_mfma_f32_16x16x32_bf16(fr.b, bm2[kk], acc, 0, 0, 0);
        }
        // lane holds T[j0+r][pt*16 + g*4 + q], q = 0..3 (D layout)
        u2[pt].x = f2bf(acc[0]) | (f2bf(acc[1]) << 16);
        u2[pt].y = f2bf(acc[2]) | (f2bf(acc[3]) << 16);
    }

    // ---- per-wave repack: D layout (4-consec p) -> B-fragment (8-consec p)
    // In-wave DS ops processed in order -> no barrier needed (R4/R10-proven).
    unsigned char* scr = lds + SCR + w * 1024;
    bf16x8 bfrag[4];
    #pragma unroll
    for (int kk = 0; kk < 4; ++kk) {
        *(uint2*)(scr + (g)     * 128 + r * 8) = u2[2 * kk];
        *(uint2*)(scr + (4 + g) * 128 + r * 8) = u2[2 * kk + 1];
        const uint2 lo2 = *(const uint2*)(scr + (2 * g)     * 128 + r * 8);
        const uint2 hi2 = *(const uint2*)(scr + (2 * g + 1) * 128 + r * 8);
        union { uint4 u; bf16x8 b; } cv;
        cv.u = make_uint4(lo2.x, lo2.y, hi2.x, hi2.y);
        bfrag[kk] = cv.b;
    }

    // ---- Stage B: out[i][j0+r] = sum_p M1[i][p] * T[j0+r][p] ----
    // A-fragments from GLOBAL fragment-major M1 (coalesced, L1/L2-hot).
    const int jc = j0 + r;
    #pragma unroll
    for (int it = 0; it < 9; ++it) {
        f32x4 acc = {0.f, 0.f, 0.f, 0.f};
        #pragma unroll
        for (int kk = 0; kk < 4; ++kk) {
            bf16x8 a = *(const bf16x8*)(M1f + (size_t)(it * 4 + kk) * 512 + lane * 8);
            acc = __builtin_amdgcn_mfma_f32_16x16x32_bf16(a, bfrag[kk], acc, 0, 0, 0);
        }
        if (jc < NH) {
            #pragma unroll
            for (int q = 0; q < 4; ++q) {
                const int i = it * 16 + g * 4 + q;
                if (i < NH) os[(size_t)i * NH + jc] = acc[q];
            }
        }
    }
}

extern "C" void kernel_launch(void* const* d_in, const int* in_sizes, int n_in,
                              void* d_out, int out_size, void* d_ws, size_t ws_size,
                              hipStream_t stream) {
    const float* x  = (const float*)d_in[0];
    const float* rw = (const float*)d_in[1];
    float* outp = (float*)d_out;
    unsigned short* M1 = (unsigned short*)d_ws;     // 18432 ushorts, fragment-major
    unsigned short* M2 = M1 + 18432;                // 18432 ushorts, row-major

    prep_M<<<dim3(2 * NP), dim3(128), 0, stream>>>(rw, M1, M2);
    dct_resize<<<dim3(NSLICE), dim3(NT), 0, stream>>>(x, M1, M2, outp);
}

// Round 17
// 72.169 us; speedup vs baseline: 1.3697x; 1.3697x over previous
//
#include <hip/hip_runtime.h>
#include <hip/hip_bf16.h>
#include <math.h>

#define NSLICE 2048
#define NH 133     // output spatial size (int(128*1+4)+1)
#define NP 144     // padded to 9 tiles of 16
#define NT 576     // 9 waves per block
#define SPB 8      // slices per block -> 256 blocks = 1/CU, ONE generation
#define NBLK (NSLICE / SPB)

// LDS map (144,384 B -> 1 block/CU):
//   [0, 65536)        Xbuf fp32, HALF-FRAGMENT-major: 64 hf x 1024 B
//                     hf=(pt*4+kk)*2+h; lane's 16B at hf*1024+lane*16 =
//                     X[pt*16+(lane&15)][kk*32+(lane>>4)*8+h*4 ..+3]
//   [65536, 98304)    X_fm bf16 fragment-major: 32 frags x 1024 B
//   [98304, 135168)   M1_fm bf16 fragment-major: 36 frags x 1024 B
//   [135168, 144384)  scratch: 9 waves x 1024 B (per-wave repack)
#define XFM  65536
#define M1B  98304
#define SCR  135168
#define LDSB 144384

typedef __attribute__((ext_vector_type(8))) short bf16x8;   // 8 bf16 = 4 VGPRs
typedef __attribute__((ext_vector_type(4))) float f32x4;

typedef __attribute__((address_space(3))) unsigned int  lds_u32;
typedef const __attribute__((address_space(1))) unsigned int glb_u32;

#define GLOAD_LDS16(gsrc, ldst) \
    __builtin_amdgcn_global_load_lds((glb_u32*)(gsrc), (lds_u32*)(ldst), 16, 0, 0)

__device__ __forceinline__ unsigned f2bf(float f) {
    __hip_bfloat16 h = __float2bfloat16(f);   // round-to-nearest-even
    union { __hip_bfloat16 b; unsigned short u; } c; c.b = h; return (unsigned)c.u;
}

// ---------------------------------------------------------------------------
// prep_M: combined (IDCT * mask * DCT) matrices, bf16, in workspace.
//   M[row, p] = sum_{u=0}^{127} D2[u,row] * mask[u] * D1[u,p]
// M1 emitted FRAGMENT-MAJOR (R10-proven); M2 row-major.
// ---------------------------------------------------------------------------
__global__ void prep_M(const float* __restrict__ rw,
                       unsigned short* __restrict__ M1,
                       unsigned short* __restrict__ M2) {
    __shared__ float t1[512];
    __shared__ float t2[532];
    const int b   = blockIdx.x;        // 0..287
    const int m   = b / NP;            // 0 -> M1, 1 -> M2
    const int row = b - m * NP;        // 0..143
    const int p   = threadIdx.x;       // 0..127

    const float c1  = (float)(M_PI / 256.0);
    const float c2  = (float)(M_PI / 266.0);
    const float s1n = 0.125f;                  // sqrt(2/128)
    const float s10 = 0.08838834764831844f;    // s1n/sqrt(2)
    const float s2n = 0.12262786485246718f;    // sqrt(2/133)
    const float s20 = 0.08671099951921386f;    // s2n/sqrt(2)

    for (int k = p; k < 512; k += 128) t1[k] = cosf((float)k * c1) * s1n;
    for (int k = p; k < 532; k += 128) t2[k] = cosf((float)k * c2) * s2n;
    __syncthreads();

    float val = 0.0f;
    if (row < NH) {
        float r = rw[m];
        float minr = fmaxf((1.0f - 4.0f) / 128.0f, 0.0f);
        r = fminf(fmaxf(r, minr), 2.0f);
        const float crop = 128.0f * r;

        const int tp = 2 * p + 1;
        const int ti = 2 * row + 1;
        float acc = s10 * s20;        // u = 0 term (mask(0) == 1 since crop >= 0)
        int a1 = 0, a2 = 0;
        for (int u = 1; u < 128; ++u) {
            a1 = (a1 + tp) & 511;
            a2 += ti; if (a2 >= 532) a2 -= 532;
            float mask = fminf(fmaxf((4.0f + crop - (float)u) * 0.25f, 0.0f), 1.0f);
            acc = fmaf(t1[a1] * mask, t2[a2], acc);
        }
        val = acc;
    }
    const unsigned short v16 = (unsigned short)f2bf(val);
    if (m == 0) {
        const int it = row >> 4, rr = row & 15;
        const int k2 = p >> 5, gg = (p >> 3) & 3, e = p & 7;
        M1[(size_t)((it * 4 + k2) * 512 + (gg * 16 + rr) * 8 + e)] = v16;
    } else {
        M2[(size_t)row * 128 + p] = v16;
    }
}

// ---------------------------------------------------------------------------
// dct_resize: 256 persistent blocks (1/CU), 9 waves, 8 slices each.
// Per slice: Xbuf(s) already resident ->
//   cvt pass (once, cooperative): Xbuf fp32 -> X_fm bf16 (all lane-contig)
//   BARRIER ; fire-and-forget gload_lds(s+1 -> Xbuf) (hides under compute)
//   Stage A (X_fm, reg bm2) ; per-wave repack ; Stage B (LDS M1_fm) ; stores
//   BARRIER (built-in vmcnt(0) drains gload_lds + stores; no manual counts)
// Prologue pays slice-0 staging + M1_fm copy ONCE PER KERNEL.
// All LDS access lane-contiguous fragment-major (proven 295K conflicts).
// ---------------------------------------------------------------------------
__global__ __launch_bounds__(NT, 2) void dct_resize(
        const float* __restrict__ x,
        const unsigned short* __restrict__ M1f,
        const unsigned short* __restrict__ M2,
        float* __restrict__ out) {
    __shared__ __align__(16) unsigned char lds[LDSB];

    const int tid  = threadIdx.x;
    const int w    = tid >> 6;      // wave 0..8
    const int lane = tid & 63;
    const int r    = lane & 15;     // fragment row/col index
    const int g    = lane >> 4;     // k-group 0..3

    const float* xbase = x   + (size_t)blockIdx.x * SPB * (128 * 128);
    float*       obase = out + (size_t)blockIdx.x * SPB * (NH * NH);

    const int j0 = w * 16;          // this wave's output-column tile

    // async staging of one slice into Xbuf (64 x 16B-granule instructions)
    #define ISSUE_X(sl) do { if (w < 8) {                                      \
        const float* _xs = xbase + (size_t)(sl) * (128 * 128);                 \
        _Pragma("unroll")                                                      \
        for (int v = 0; v < 8; ++v) {                                          \
            const int hf = w * 8 + v;                                          \
            const int f_ = hf >> 1, h_ = hf & 1;                               \
            const int pt_ = f_ >> 2, k2_ = f_ & 3;                             \
            const float* _src = _xs + (size_t)(pt_ * 16 + r) * 128             \
                              + k2_ * 32 + g * 8 + h_ * 4;                     \
            GLOAD_LDS16(_src, lds + hf * 1024);   /* HW adds lane*16 */        \
        } } } while (0)

    // ---- prologue: M1_fm copy + slice 0 staging (all async) + bm2 regs ----
    #pragma unroll
    for (int v = 0; v < 4; ++v)
        GLOAD_LDS16(M1f + (size_t)(v * NT + tid) * 8,
                    lds + M1B + (v * NT + tid) * 16);
    ISSUE_X(0);

    bf16x8 bm2[4];
    #pragma unroll
    for (int kk = 0; kk < 4; ++kk)
        bm2[kk] = *(const bf16x8*)(M2 + (size_t)(j0 + r) * 128 + kk * 32 + g * 8);

    __syncthreads();   // vmcnt(0) built in: M1_fm + Xbuf(slice 0) resident

    for (int s = 0; s < SPB; ++s) {
        // ---- cooperative cvt: Xbuf -> X_fm (each value converted ONCE) ----
        // thread t<512 handles granules (f = v*8 + w, l = lane), v = 0..3
        if (w < 8) {
            #pragma unroll
            for (int v = 0; v < 4; ++v) {
                const int f = v * 8 + w;
                const float4 lo = *(const float4*)(lds + (2 * f) * 1024 + lane * 16);
                const float4 hi = *(const float4*)(lds + (2 * f + 1) * 1024 + lane * 16);
                uint4 pkt;
                pkt.x = f2bf(lo.x) | (f2bf(lo.y) << 16);
                pkt.y = f2bf(lo.z) | (f2bf(lo.w) << 16);
                pkt.z = f2bf(hi.x) | (f2bf(hi.y) << 16);
                pkt.w = f2bf(hi.z) | (f2bf(hi.w) << 16);
                *(uint4*)(lds + XFM + f * 1024 + lane * 16) = pkt;
            }
        }
        __syncthreads();   // X_fm ready; Xbuf dead -> safe to restage

        if (s + 1 < SPB) ISSUE_X(s + 1);   // fire-and-forget, hides under A+B

        // ---- Stage A: T[j0+r][p] = sum_q X[p][q] * M2[j0+r][q] ----
        uint2 u2[8];
        #pragma unroll
        for (int pt = 0; pt < 8; ++pt) {
            f32x4 acc = {0.f, 0.f, 0.f, 0.f};
            #pragma unroll
            for (int kk = 0; kk < 4; ++kk) {
                bf16x8 a = *(const bf16x8*)(lds + XFM + (pt * 4 + kk) * 1024 + lane * 16);
                acc = __builtin_amdgcn_mfma_f32_16x16x32_bf16(a, bm2[kk], acc, 0, 0, 0);
            }
            u2[pt].x = f2bf(acc[0]) | (f2bf(acc[1]) << 16);
            u2[pt].y = f2bf(acc[2]) | (f2bf(acc[3]) << 16);
        }

        // ---- per-wave repack: D layout (4-consec p) -> B-frag (8-consec p)
        // In-wave DS ordering -> barrier-free (R4/R10-proven).
        unsigned char* scr = lds + SCR + w * 1024;
        bf16x8 bfrag[4];
        #pragma unroll
        for (int kk = 0; kk < 4; ++kk) {
            *(uint2*)(scr + (g)     * 128 + r * 8) = u2[2 * kk];
            *(uint2*)(scr + (4 + g) * 128 + r * 8) = u2[2 * kk + 1];
            const uint2 lo2 = *(const uint2*)(scr + (2 * g)     * 128 + r * 8);
            const uint2 hi2 = *(const uint2*)(scr + (2 * g + 1) * 128 + r * 8);
            union { uint4 u; bf16x8 b; } cv;
            cv.u = make_uint4(lo2.x, lo2.y, hi2.x, hi2.y);
            bfrag[kk] = cv.b;
        }

        // ---- Stage B: out[i][j0+r] = sum_p M1[i][p] * T[j0+r][p] ----
        float* os = obase + (size_t)s * (NH * NH);
        const int jc = j0 + r;
        #pragma unroll
        for (int it = 0; it < 9; ++it) {
            f32x4 acc = {0.f, 0.f, 0.f, 0.f};
            #pragma unroll
            for (int kk = 0; kk < 4; ++kk) {
                bf16x8 a = *(const bf16x8*)(lds + M1B + (it * 4 + kk) * 1024 + lane * 16);
                acc = __builtin_amdgcn_mfma_f32_16x16x32_bf16(a, bfrag[kk], acc, 0, 0, 0);
            }
            if (jc < NH) {
                #pragma unroll
                for (int q = 0; q < 4; ++q) {
                    const int i = it * 16 + g * 4 + q;
                    if (i < NH) os[(size_t)i * NH + jc] = acc[q];
                }
            }
        }

        __syncthreads();   // drains gload_lds(s+1) + stores; X_fm free
    }
    #undef ISSUE_X
}

extern "C" void kernel_launch(void* const* d_in, const int* in_sizes, int n_in,
                              void* d_out, int out_size, void* d_ws, size_t ws_size,
                              hipStream_t stream) {
    const float* x  = (const float*)d_in[0];
    const float* rw = (const float*)d_in[1];
    float* outp = (float*)d_out;
    unsigned short* M1 = (unsigned short*)d_ws;     // 18432 ushorts, fragment-major
    unsigned short* M2 = M1 + 18432;                // 18432 ushorts, row-major

    prep_M<<<dim3(2 * NP), dim3(128), 0, stream>>>(rw, M1, M2);
    dct_resize<<<dim3(NBLK), dim3(NT), 0, stream>>>(x, M1, M2, outp);
}

// Round 18
// 70.529 us; speedup vs baseline: 1.4015x; 1.0233x over previous
//
#include <hip/hip_runtime.h>
#include <hip/hip_bf16.h>
#include <math.h>

#define NSLICE 2048
#define NH 133     // output spatial size (int(128*1+4)+1)
#define NP 144     // padded to 9 tiles of 16
#define NT 576     // 9 waves per block
#define SPB 8      // slices per block -> 256 blocks = 1/CU, ONE generation
#define NBLK (NSLICE / SPB)

// LDS map (144,384 B -> 1 block/CU):
//   [0, 65536)        Xbuf fp32, HALF-FRAGMENT-major: 64 hf x 1024 B
//                     hf=(pt*4+kk)*2+h; lane's 16B at hf*1024+lane*16 =
//                     X[pt*16+(lane&15)][kk*32+(lane>>4)*8+h*4 ..+3]
//   [65536, 98304)    X_fm bf16 fragment-major: 32 frags x 1024 B
//   [98304, 135168)   M1_fm bf16 fragment-major: 36 frags x 1024 B
//   [135168, 144384)  scratch: 9 waves x 1024 B (per-wave repack)
#define XFM  65536
#define M1B  98304
#define SCR  135168
#define LDSB 144384

typedef __attribute__((ext_vector_type(8))) short bf16x8;   // 8 bf16 = 4 VGPRs
typedef __attribute__((ext_vector_type(4))) float f32x4;

typedef __attribute__((address_space(3))) unsigned int  lds_u32;
typedef const __attribute__((address_space(1))) unsigned int glb_u32;

#define GLOAD_LDS16(gsrc, ldst) \
    __builtin_amdgcn_global_load_lds((glb_u32*)(gsrc), (lds_u32*)(ldst), 16, 0, 0)

#define LGKM0 asm volatile("s_waitcnt lgkmcnt(0)" ::: "memory")
// end-of-slice wait: per-wave queue = [8 gloads(s+1)][36 stores] -> vmcnt(36)
// retires exactly the gloads; stores drain in background.
#define VMW36 asm volatile("s_waitcnt vmcnt(36)" ::: "memory")
// raw barrier, fenced; vmcnt deliberately NOT drained (stores stay in flight)
#define BAR() do { __builtin_amdgcn_sched_barrier(0); \
                   asm volatile("s_waitcnt lgkmcnt(0)" ::: "memory"); \
                   __builtin_amdgcn_s_barrier(); \
                   __builtin_amdgcn_sched_barrier(0); } while (0)

__device__ __forceinline__ unsigned f2bf(float f) {
    __hip_bfloat16 h = __float2bfloat16(f);   // round-to-nearest-even
    union { __hip_bfloat16 b; unsigned short u; } c; c.b = h; return (unsigned)c.u;
}

// ---------------------------------------------------------------------------
// prep_M: combined (IDCT * mask * DCT) matrices, bf16, in workspace.
//   M[row, p] = sum_{u=0}^{127} D2[u,row] * mask[u] * D1[u,p]
// M1 emitted FRAGMENT-MAJOR (R10-proven); M2 row-major.
// ---------------------------------------------------------------------------
__global__ void prep_M(const float* __restrict__ rw,
                       unsigned short* __restrict__ M1,
                       unsigned short* __restrict__ M2) {
    __shared__ float t1[512];
    __shared__ float t2[532];
    const int b   = blockIdx.x;        // 0..287
    const int m   = b / NP;            // 0 -> M1, 1 -> M2
    const int row = b - m * NP;        // 0..143
    const int p   = threadIdx.x;       // 0..127

    const float c1  = (float)(M_PI / 256.0);
    const float c2  = (float)(M_PI / 266.0);
    const float s1n = 0.125f;                  // sqrt(2/128)
    const float s10 = 0.08838834764831844f;    // s1n/sqrt(2)
    const float s2n = 0.12262786485246718f;    // sqrt(2/133)
    const float s20 = 0.08671099951921386f;    // s2n/sqrt(2)

    for (int k = p; k < 512; k += 128) t1[k] = cosf((float)k * c1) * s1n;
    for (int k = p; k < 532; k += 128) t2[k] = cosf((float)k * c2) * s2n;
    __syncthreads();

    float val = 0.0f;
    if (row < NH) {
        float r = rw[m];
        float minr = fmaxf((1.0f - 4.0f) / 128.0f, 0.0f);
        r = fminf(fmaxf(r, minr), 2.0f);
        const float crop = 128.0f * r;

        const int tp = 2 * p + 1;
        const int ti = 2 * row + 1;
        float acc = s10 * s20;        // u = 0 term (mask(0) == 1 since crop >= 0)
        int a1 = 0, a2 = 0;
        for (int u = 1; u < 128; ++u) {
            a1 = (a1 + tp) & 511;
            a2 += ti; if (a2 >= 532) a2 -= 532;
            float mask = fminf(fmaxf((4.0f + crop - (float)u) * 0.25f, 0.0f), 1.0f);
            acc = fmaf(t1[a1] * mask, t2[a2], acc);
        }
        val = acc;
    }
    const unsigned short v16 = (unsigned short)f2bf(val);
    if (m == 0) {
        const int it = row >> 4, rr = row & 15;
        const int k2 = p >> 5, gg = (p >> 3) & 3, e = p & 7;
        M1[(size_t)((it * 4 + k2) * 512 + (gg * 16 + rr) * 8 + e)] = v16;
    } else {
        M2[(size_t)row * 128 + p] = v16;
    }
}

// ---------------------------------------------------------------------------
// dct_resize: 256 persistent blocks (1/CU), 9 waves, 8 slices each.
// R17 + store-drain removal. Ownership-aligned pipeline: wave w stages AND
// converts Xbuf granules hf in [8w, 8w+8) (-> X_fm frags [4w, 4w+4)), so
// every wait is per-wave-local:
//   slice s: cvt own region (Xbuf -> X_fm) ; LGKM0 ; issue gloads(s+1)
//            BAR (X_fm visible) ; Stage A ; repack ; Stage B (36 stores)
//            VMW36 (gloads retired, stores in flight) ; BAR
// Stores drain in background during the next slice's cvt + stage A.
// All LDS access lane-contiguous fragment-major (proven 295K conflicts).
// ---------------------------------------------------------------------------
__global__ __launch_bounds__(NT, 2) void dct_resize(
        const float* __restrict__ x,
        const unsigned short* __restrict__ M1f,
        const unsigned short* __restrict__ M2,
        float* __restrict__ out) {
    __shared__ __align__(16) unsigned char lds[LDSB];

    const int tid  = threadIdx.x;
    const int w    = tid >> 6;      // wave 0..8
    const int lane = tid & 63;
    const int r    = lane & 15;     // fragment row/col index
    const int g    = lane >> 4;     // k-group 0..3

    const float* xbase = x   + (size_t)blockIdx.x * SPB * (128 * 128);
    float*       obase = out + (size_t)blockIdx.x * SPB * (NH * NH);

    const int j0 = w * 16;          // this wave's output-column tile

    // async staging of one slice into Xbuf; wave w owns hf in [8w, 8w+8)
    #define ISSUE_X(sl) do { if (w < 8) {                                      \
        const float* _xs = xbase + (size_t)(sl) * (128 * 128);                 \
        _Pragma("unroll")                                                      \
        for (int v = 0; v < 8; ++v) {                                          \
            const int hf = w * 8 + v;                                          \
            const int f_ = hf >> 1, h_ = hf & 1;                               \
            const int pt_ = f_ >> 2, k2_ = f_ & 3;                             \
            const float* _src = _xs + (size_t)(pt_ * 16 + r) * 128             \
                              + k2_ * 32 + g * 8 + h_ * 4;                     \
            GLOAD_LDS16(_src, lds + hf * 1024);   /* HW adds lane*16 */        \
        } } } while (0)

    // ---- prologue: M1_fm copy + slice 0 staging (all async) + bm2 regs ----
    #pragma unroll
    for (int v = 0; v < 4; ++v)
        GLOAD_LDS16(M1f + (size_t)(v * NT + tid) * 8,
                    lds + M1B + (v * NT + tid) * 16);
    ISSUE_X(0);

    bf16x8 bm2[4];
    #pragma unroll
    for (int kk = 0; kk < 4; ++kk)
        bm2[kk] = *(const bf16x8*)(M2 + (size_t)(j0 + r) * 128 + kk * 32 + g * 8);

    __syncthreads();   // vmcnt(0) built in: M1_fm + Xbuf(slice 0) resident

    for (int s = 0; s < SPB; ++s) {
        // ---- cvt OWN region: Xbuf hf[8w..8w+8) -> X_fm frags [4w..4w+4) ----
        if (w < 8) {
            #pragma unroll
            for (int v = 0; v < 4; ++v) {
                const int f = 4 * w + v;
                const float4 lo = *(const float4*)(lds + (2 * f) * 1024 + lane * 16);
                const float4 hi = *(const float4*)(lds + (2 * f + 1) * 1024 + lane * 16);
                uint4 pkt;
                pkt.x = f2bf(lo.x) | (f2bf(lo.y) << 16);
                pkt.y = f2bf(lo.z) | (f2bf(lo.w) << 16);
                pkt.z = f2bf(hi.x) | (f2bf(hi.y) << 16);
                pkt.w = f2bf(hi.z) | (f2bf(hi.w) << 16);
                *(uint4*)(lds + XFM + f * 1024 + lane * 16) = pkt;
            }
        }
        // own cvt reads complete -> safe to let HW overwrite own Xbuf region
        LGKM0;
        if (s + 1 < SPB) ISSUE_X(s + 1);   // fire-and-forget

        BAR();   // all X_fm writes visible to all waves

        // ---- Stage A: T[j0+r][p] = sum_q X[p][q] * M2[j0+r][q] ----
        uint2 u2[8];
        #pragma unroll
        for (int pt = 0; pt < 8; ++pt) {
            f32x4 acc = {0.f, 0.f, 0.f, 0.f};
            #pragma unroll
            for (int kk = 0; kk < 4; ++kk) {
                bf16x8 a = *(const bf16x8*)(lds + XFM + (pt * 4 + kk) * 1024 + lane * 16);
                acc = __builtin_amdgcn_mfma_f32_16x16x32_bf16(a, bm2[kk], acc, 0, 0, 0);
            }
            u2[pt].x = f2bf(acc[0]) | (f2bf(acc[1]) << 16);
            u2[pt].y = f2bf(acc[2]) | (f2bf(acc[3]) << 16);
        }

        // ---- per-wave repack: D layout (4-consec p) -> B-frag (8-consec p)
        // In-wave DS ordering -> barrier-free (R4/R10-proven).
        unsigned char* scr = lds + SCR + w * 1024;
        bf16x8 bfrag[4];
        #pragma unroll
        for (int kk = 0; kk < 4; ++kk) {
            *(uint2*)(scr + (g)     * 128 + r * 8) = u2[2 * kk];
            *(uint2*)(scr + (4 + g) * 128 + r * 8) = u2[2 * kk + 1];
            const uint2 lo2 = *(const uint2*)(scr + (2 * g)     * 128 + r * 8);
            const uint2 hi2 = *(const uint2*)(scr + (2 * g + 1) * 128 + r * 8);
            union { uint4 u; bf16x8 b; } cv;
            cv.u = make_uint4(lo2.x, lo2.y, hi2.x, hi2.y);
            bfrag[kk] = cv.b;
        }

        // ---- Stage B: out[i][j0+r] = sum_p M1[i][p] * T[j0+r][p] ----
        float* os = obase + (size_t)s * (NH * NH);
        const int jc = j0 + r;
        #pragma unroll
        for (int it = 0; it < 9; ++it) {
            f32x4 acc = {0.f, 0.f, 0.f, 0.f};
            #pragma unroll
            for (int kk = 0; kk < 4; ++kk) {
                bf16x8 a = *(const bf16x8*)(lds + M1B + (it * 4 + kk) * 1024 + lane * 16);
                acc = __builtin_amdgcn_mfma_f32_16x16x32_bf16(a, bfrag[kk], acc, 0, 0, 0);
            }
            if (jc < NH) {
                #pragma unroll
                for (int q = 0; q < 4; ++q) {
                    const int i = it * 16 + g * 4 + q;
                    if (i < NH) os[(size_t)i * NH + jc] = acc[q];
                }
            }
        }

        // ---- slice boundary: retire ONLY the gloads; stores keep flying ----
        VMW36;   // queue: [8 gloads][36 stores] -> oldest 8 retired
        BAR();   // X_fm(s) reads done everywhere; next cvt may overwrite
    }
    #undef ISSUE_X
}

extern "C" void kernel_launch(void* const* d_in, const int* in_sizes, int n_in,
                              void* d_out, int out_size, void* d_ws, size_t ws_size,
                              hipStream_t stream) {
    const float* x  = (const float*)d_in[0];
    const float* rw = (const float*)d_in[1];
    float* outp = (float*)d_out;
    unsigned short* M1 = (unsigned short*)d_ws;     // 18432 ushorts, fragment-major
    unsigned short* M2 = M1 + 18432;                // 18432 ushorts, row-major

    prep_M<<<dim3(2 * NP), dim3(128), 0, stream>>>(rw, M1, M2);
    dct_resize<<<dim3(NBLK), dim3(NT), 0, stream>>>(x, M1, M2, outp);
}